// Round 1
// baseline (256.091 us; speedup 1.0000x reference)
//
#include <hip/hip_runtime.h>

typedef __attribute__((ext_vector_type(8))) short short8;
typedef __attribute__((ext_vector_type(4))) float f32x4;

#define T_TOK 16384
#define DM 512
#define NE 8
#define BM 64

__device__ __forceinline__ ushort f2bf(float v) {
  unsigned u = __float_as_uint(v);
  return (ushort)((u + 0x7FFFu + ((u >> 16) & 1u)) >> 16);
}

// ---------------- gating: logits + softmax, one wave per token ----------------
__global__ void gates_kernel(const float* __restrict__ x, const float* __restrict__ Wg,
                             const float* __restrict__ bg, float* __restrict__ gates) {
  int wid = (int)((blockIdx.x * blockDim.x + threadIdx.x) >> 6);
  int lane = threadIdx.x & 63;
  if (wid >= T_TOK) return;
  const float* xt = x + (size_t)wid * DM;
  float a[NE];
#pragma unroll
  for (int e = 0; e < NE; ++e) a[e] = 0.f;
  for (int d = lane; d < DM; d += 64) {
    float xv = xt[d];
    const float* wr = Wg + d * NE;
#pragma unroll
    for (int e = 0; e < NE; ++e) a[e] += xv * wr[e];
  }
#pragma unroll
  for (int e = 0; e < NE; ++e) {
#pragma unroll
    for (int off = 32; off > 0; off >>= 1) a[e] += __shfl_xor(a[e], off, 64);
  }
  float m = -1e30f;
#pragma unroll
  for (int e = 0; e < NE; ++e) { a[e] += bg[e]; m = fmaxf(m, a[e]); }
  float s = 0.f;
#pragma unroll
  for (int e = 0; e < NE; ++e) { a[e] = __expf(a[e] - m); s += a[e]; }
  float inv = 1.f / s;
  if (lane < NE) gates[(size_t)wid * NE + lane] = a[lane] * inv;
}

// -------- weight reorder: W[e][k][n] fp32 -> fragment-major bf16 ------------
// WF chunk layout: [e][kt][ntile][lane] of 16B; lane l holds
// W[e][kt*32 + (l>>4)*8 + j][ntile*16 + (l&15)] for j=0..7 (bf16).
__global__ void reorder_w_kernel(const float* __restrict__ W, ushort* __restrict__ WF) {
  int c = blockIdx.x * blockDim.x + threadIdx.x;  // 8*16*32*64 = 262144 chunks
  int l = c & 63;
  int ntg = (c >> 6) & 31;
  int kt = (c >> 11) & 15;
  int e = c >> 15;
  int n = ntg * 16 + (l & 15);
  int k0 = kt * 32 + (l >> 4) * 8;
  const float* src = W + ((size_t)e * DM + k0) * DM + n;
  short8 v;
#pragma unroll
  for (int j = 0; j < 8; ++j) v[j] = (short)f2bf(src[(size_t)j * DM]);
  *reinterpret_cast<short8*>(WF + (size_t)c * 8) = v;
}

// ---------------- fused MoE main kernel ----------------
// grid = 256 blocks (64 tokens each), 512 threads (8 waves; wave w owns n-cols [w*64, w*64+64))
__global__ __launch_bounds__(512, 2) void moe_main_kernel(
    const float* __restrict__ x, const ushort* __restrict__ W1F,
    const float* __restrict__ b1, const ushort* __restrict__ W2F,
    const float* __restrict__ b2, const float* __restrict__ gates,
    float* __restrict__ out) {
  extern __shared__ char smem[];
  char* x_lds = smem;                       // 65536 B  [64][512] bf16, swizzled
  char* h_lds = smem + 65536;               // 65536 B  [64][512] bf16, swizzled
  float* g_lds = (float*)(smem + 131072);   // 2048 B   [64][8]

  const int tid = threadIdx.x;
  const int lane = tid & 63;
  const int w = tid >> 6;
  const int q = lane >> 4;
  const int lr = lane & 15;
  const int m0 = blockIdx.x * BM;

  g_lds[tid] = gates[(size_t)m0 * NE + tid];

  // stage x tile: fp32 -> bf16, XOR-swizzled rows (row stride 1024B)
  for (int i = tid; i < BM * DM / 4; i += 512) {
    int t = i >> 7;           // /128 float4s per row
    int kd = (i & 127) * 4;
    float4 v = *reinterpret_cast<const float4*>(x + ((size_t)(m0 + t) << 9) + kd);
    unsigned lo = (unsigned)f2bf(v.x) | ((unsigned)f2bf(v.y) << 16);
    unsigned hi = (unsigned)f2bf(v.z) | ((unsigned)f2bf(v.w) << 16);
    unsigned off = ((unsigned)(t * 1024 + kd * 2)) ^ (((unsigned)(t & 7)) << 4);
    *reinterpret_cast<uint2*>(x_lds + off) = make_uint2(lo, hi);
  }
  __syncthreads();

  f32x4 acc[4][4];
#pragma unroll
  for (int a_ = 0; a_ < 4; ++a_)
#pragma unroll
    for (int b_ = 0; b_ < 4; ++b_) acc[a_][b_] = (f32x4){0.f, 0.f, 0.f, 0.f};

  const unsigned a_base = (unsigned)(lr * 1024 + q * 16);
  const unsigned a_swz = ((unsigned)(lane & 7)) << 4;

  for (int e = 0; e < NE; ++e) {
    // ---------- GEMM1: hacc = x @ W1[e] ----------
    const short8* w1p = reinterpret_cast<const short8*>(W1F) + (size_t)e * 32768 + w * 256 + lane;
    f32x4 hacc[4][4];
#pragma unroll
    for (int a_ = 0; a_ < 4; ++a_)
#pragma unroll
      for (int b_ = 0; b_ < 4; ++b_) hacc[a_][b_] = (f32x4){0.f, 0.f, 0.f, 0.f};

    short8 bcur[4], bnxt[4];
#pragma unroll
    for (int nt = 0; nt < 4; ++nt) bcur[nt] = w1p[nt * 64];
#pragma unroll
    for (int kt = 0; kt < 16; ++kt) {
      if (kt < 15) {
#pragma unroll
        for (int nt = 0; nt < 4; ++nt) bnxt[nt] = w1p[(kt + 1) * 2048 + nt * 64];
      }
      short8 afr[4];
#pragma unroll
      for (int mt = 0; mt < 4; ++mt) {
        unsigned off = ((unsigned)(a_base + mt * 16384 + kt * 64)) ^ a_swz;
        afr[mt] = *reinterpret_cast<const short8*>(x_lds + off);
      }
#pragma unroll
      for (int mt = 0; mt < 4; ++mt)
#pragma unroll
        for (int nt = 0; nt < 4; ++nt)
          hacc[mt][nt] = __builtin_amdgcn_mfma_f32_16x16x32_bf16(afr[mt], bcur[nt], hacc[mt][nt], 0, 0, 0);
      if (kt < 15) {
#pragma unroll
        for (int nt = 0; nt < 4; ++nt) bcur[nt] = bnxt[nt];
      }
    }

    // epilogue: h = relu(hacc + b1) * gate -> h_lds (bf16, swizzled)
    float b1v[4];
#pragma unroll
    for (int nt = 0; nt < 4; ++nt) b1v[nt] = b1[e * DM + w * 64 + nt * 16 + lr];
#pragma unroll
    for (int mt = 0; mt < 4; ++mt) {
#pragma unroll
      for (int i = 0; i < 4; ++i) {
        int t = mt * 16 + q * 4 + i;
        float g = g_lds[t * NE + e];
        unsigned rswz = ((unsigned)(t & 7)) << 4;
#pragma unroll
        for (int nt = 0; nt < 4; ++nt) {
          int f = w * 64 + nt * 16 + lr;
          float v = fmaxf(hacc[mt][nt][i] + b1v[nt], 0.f) * g;
          unsigned off = ((unsigned)(t * 1024 + f * 2)) ^ rswz;
          *reinterpret_cast<ushort*>(h_lds + off) = f2bf(v);
        }
      }
    }
    __syncthreads();

    // ---------- GEMM2: acc += (g*h) @ W2[e] ----------
    const short8* w2p = reinterpret_cast<const short8*>(W2F) + (size_t)e * 32768 + w * 256 + lane;
#pragma unroll
    for (int nt = 0; nt < 4; ++nt) bcur[nt] = w2p[nt * 64];
#pragma unroll
    for (int kt = 0; kt < 16; ++kt) {
      if (kt < 15) {
#pragma unroll
        for (int nt = 0; nt < 4; ++nt) bnxt[nt] = w2p[(kt + 1) * 2048 + nt * 64];
      }
      short8 afr[4];
#pragma unroll
      for (int mt = 0; mt < 4; ++mt) {
        unsigned off = ((unsigned)(a_base + mt * 16384 + kt * 64)) ^ a_swz;
        afr[mt] = *reinterpret_cast<const short8*>(h_lds + off);
      }
#pragma unroll
      for (int mt = 0; mt < 4; ++mt)
#pragma unroll
        for (int nt = 0; nt < 4; ++nt)
          acc[mt][nt] = __builtin_amdgcn_mfma_f32_16x16x32_bf16(afr[mt], bcur[nt], acc[mt][nt], 0, 0, 0);
      if (kt < 15) {
#pragma unroll
        for (int nt = 0; nt < 4; ++nt) bcur[nt] = bnxt[nt];
      }
    }

    // fold gate * b2
    float b2v[4];
#pragma unroll
    for (int nt = 0; nt < 4; ++nt) b2v[nt] = b2[e * DM + w * 64 + nt * 16 + lr];
#pragma unroll
    for (int mt = 0; mt < 4; ++mt)
#pragma unroll
      for (int i = 0; i < 4; ++i) {
        int t = mt * 16 + q * 4 + i;
        float g = g_lds[t * NE + e];
#pragma unroll
        for (int nt = 0; nt < 4; ++nt) acc[mt][nt][i] += g * b2v[nt];
      }
    __syncthreads();
  }

  // write out (fp32)
#pragma unroll
  for (int mt = 0; mt < 4; ++mt)
#pragma unroll
    for (int i = 0; i < 4; ++i) {
      int t = mt * 16 + q * 4 + i;
      float* op = out + ((size_t)(m0 + t)) * DM + w * 64 + lr;
#pragma unroll
      for (int nt = 0; nt < 4; ++nt) op[nt * 16] = acc[mt][nt][i];
    }
}

extern "C" void kernel_launch(void* const* d_in, const int* in_sizes, int n_in,
                              void* d_out, int out_size, void* d_ws, size_t ws_size,
                              hipStream_t stream) {
  const float* x  = (const float*)d_in[0];
  const float* W1 = (const float*)d_in[1];
  const float* b1 = (const float*)d_in[2];
  const float* W2 = (const float*)d_in[3];
  const float* b2 = (const float*)d_in[4];
  const float* Wg = (const float*)d_in[5];
  const float* bg = (const float*)d_in[6];
  float* out = (float*)d_out;

  float* gates = (float*)d_ws;                              // 524288 B
  ushort* W1F = (ushort*)((char*)d_ws + 524288);            // 4 MiB
  ushort* W2F = (ushort*)((char*)d_ws + 524288 + 4194304);  // 4 MiB

  // allow >64KB dynamic LDS (graph-capture-safe: host-side attribute, no enqueue)
  hipFuncSetAttribute((const void*)moe_main_kernel,
                      hipFuncAttributeMaxDynamicSharedMemorySize, 133120);

  gates_kernel<<<T_TOK / 4, 256, 0, stream>>>(x, Wg, bg, gates);
  reorder_w_kernel<<<1024, 256, 0, stream>>>(W1, W1F);
  reorder_w_kernel<<<1024, 256, 0, stream>>>(W2, W2F);
  moe_main_kernel<<<T_TOK / BM, 512, 133120, stream>>>(x, W1F, b1, W2F, b2, gates, out);
}